// Round 1
// baseline (148.363 us; speedup 1.0000x reference)
//
#include <hip/hip_runtime.h>
#include <math.h>

// ---- problem constants ----
constexpr int   Hh    = 8;
constexpr float DC_S  = 0.01f;
constexpr int   DC_BW = 16;
constexpr float STOP_W = 8.0f;
constexpr int Bn = 16, Tn = 800, Sn = 160, NM = 80, Ln = 4;
constexpr int Kk = Tn / Sn;                 // 5
constexpr int MEL4   = Bn * Tn * NM / 4;    // 256000 float4 items
constexpr int DCI    = Ln * Bn * Hh * Sn;   // 81920 (l,bh,s) items
constexpr int NITEMS = MEL4 + DCI;
constexpr int BLK    = 256;
constexpr int GRID   = (NITEMS + BLK - 1) / BLK;

// ws[0] = sum |mels_pred*mask - target|,  ws[1] = banded alignment sum
__global__ __launch_bounds__(BLK) void lossA(
    const int*   __restrict__ length,
    const float* __restrict__ mels_pred,
    const float* __restrict__ mels_target,
    const float* __restrict__ align,
    float*       __restrict__ ws)
{
    int i = blockIdx.x * BLK + threadIdx.x;
    float mel_acc = 0.f, dc_acc = 0.f;

    if (i < MEL4) {
        // ---- masked L1 mel term, 4 elems per thread ----
        int bt = (i * 4) / NM;          // b*T + t  (NM divisible by 4)
        int b  = bt / Tn;
        int t  = bt - b * Tn;
        float4 p = reinterpret_cast<const float4*>(mels_pred)[i];
        float4 g = reinterpret_cast<const float4*>(mels_target)[i];
        float  m = (t < length[b]) ? 1.f : 0.f;
        mel_acc = fabsf(p.x * m - g.x) + fabsf(p.y * m - g.y)
                + fabsf(p.z * m - g.z) + fabsf(p.w * m - g.w);
    } else if (i < NITEMS) {
        // ---- diagonal-constraint banded gather: one (l,bh,s) row ----
        int j   = i - MEL4;
        int s   = j % Sn;
        int lbh = j / Sn;                 // l*(B*H) + bh, layout [L, B*H, S, T]
        int bh  = lbh % (Bn * Hh);
        int b   = bh % Bn;                // head-major: bh = h*B + b
        float sm = (Tn >= length[b]) ? 1.f : 0.f;

        // band[s,t] = (s >= k*t - BW) && (s < k*t + BW)
        // t > (s-BW)/k  (real floor!)  and  t <= (s+BW)/k
        int t_lo = (s < DC_BW) ? 0 : (s - DC_BW) / Kk + 1;
        int t_hi = (s + DC_BW) / Kk + 1;          // exclusive; max 36 << Tn
        const float* row = align + ((size_t)lbh * Sn + s) * (size_t)Tn;
        float acc = 0.f;
        #pragma unroll 4
        for (int t = t_lo; t < t_hi; ++t) acc += row[t];
        dc_acc = acc * sm;
    }

    // wave64 reduce, one atomic pair per wave
    for (int off = 32; off > 0; off >>= 1) {
        mel_acc += __shfl_down(mel_acc, off);
        dc_acc  += __shfl_down(dc_acc,  off);
    }
    if ((threadIdx.x & 63) == 0) {
        atomicAdd(&ws[0], mel_acc);
        atomicAdd(&ws[1], dc_acc);
    }
}

// final combine: stop-BCE (16 samples) + normalization
__global__ void lossB(const int*   __restrict__ length,
                      const float* __restrict__ stop_pred,
                      const float* __restrict__ ws,
                      float*       __restrict__ out)
{
    float sum_len = 0.f, stop_sum = 0.f;
    for (int b = 0; b < Bn; ++b) {
        int len = length[b];
        sum_len += (float)len;
        float p  = stop_pred[b * Tn + (len - 1)];
        float lg = logf(p);
        if (lg < -100.f) lg = -100.f;
        stop_sum += -lg;                      // target=1, weight=STOP_W applied below
    }
    float mel  = ws[0] / (float)(Bn * Tn * NM);
    float stop = STOP_W * stop_sum / sum_len;
    float dc   = ws[1] / ((float)Hh * sum_len);
    out[0] = mel + stop - DC_S * dc;
}

extern "C" void kernel_launch(void* const* d_in, const int* in_sizes, int n_in,
                              void* d_out, int out_size, void* d_ws, size_t ws_size,
                              hipStream_t stream)
{
    const int*   length      = (const int*)  d_in[0];
    // d_in[1] = mask (bool) — recomputed from length (prefix mask by construction)
    const float* stop_pred   = (const float*)d_in[2];
    const float* mels_pred   = (const float*)d_in[3];
    const float* mels_target = (const float*)d_in[4];
    const float* align       = (const float*)d_in[5];
    float* out = (float*)d_out;
    float* ws  = (float*)d_ws;

    hipMemsetAsync(ws, 0, 2 * sizeof(float), stream);
    lossA<<<GRID, BLK, 0, stream>>>(length, mels_pred, mels_target, align, ws);
    lossB<<<1, 1, 0, stream>>>(length, stop_pred, ws, out);
}

// Round 2
// 14.088 us; speedup vs baseline: 10.5312x; 10.5312x over previous
//
#include <hip/hip_runtime.h>
#include <math.h>

// ---- problem constants ----
constexpr int   Hh    = 8;
constexpr float DC_S  = 0.01f;
constexpr int   DC_BW = 16;
constexpr float STOP_W = 8.0f;
constexpr int Bn = 16, Tn = 800, Sn = 160, NM = 80, Ln = 4;
constexpr int Kk = Tn / Sn;                 // 5
constexpr int MEL4   = Bn * Tn * NM / 4;    // 256000 float4 items
constexpr int DCI    = Ln * Bn * Hh * Sn;   // 81920 (l,bh,s) items
constexpr int NITEMS = MEL4 + DCI;
constexpr int BLK    = 256;
constexpr int GRID   = (NITEMS + BLK - 1) / BLK;   // 1320 blocks

// ws[2*blk] = block's sum |mels_pred*mask - target|, ws[2*blk+1] = banded align sum
__global__ __launch_bounds__(BLK) void lossA(
    const int*   __restrict__ length,
    const float* __restrict__ mels_pred,
    const float* __restrict__ mels_target,
    const float* __restrict__ align,
    float*       __restrict__ ws)
{
    int i = blockIdx.x * BLK + threadIdx.x;
    float mel_acc = 0.f, dc_acc = 0.f;

    if (i < MEL4) {
        // ---- masked L1 mel term, 4 elems per thread ----
        int bt = (i * 4) / NM;          // b*T + t  (NM divisible by 4)
        int b  = bt / Tn;
        int t  = bt - b * Tn;
        float4 p = reinterpret_cast<const float4*>(mels_pred)[i];
        float4 g = reinterpret_cast<const float4*>(mels_target)[i];
        float  m = (t < length[b]) ? 1.f : 0.f;
        mel_acc = fabsf(p.x * m - g.x) + fabsf(p.y * m - g.y)
                + fabsf(p.z * m - g.z) + fabsf(p.w * m - g.w);
    } else if (i < NITEMS) {
        // ---- diagonal-constraint banded gather: one (l,bh,s) row ----
        int j   = i - MEL4;
        int s   = j % Sn;
        int lbh = j / Sn;                 // l*(B*H) + bh, layout [L, B*H, S, T]
        int bh  = lbh % (Bn * Hh);
        int b   = bh % Bn;                // head-major: bh = h*B + b
        float sm = (Tn >= length[b]) ? 1.f : 0.f;

        // band[s,t] = (s >= k*t - BW) && (s < k*t + BW)
        // t > (s-BW)/k  (real floor!)  and  t <= (s+BW)/k
        int t_lo = (s < DC_BW) ? 0 : (s - DC_BW) / Kk + 1;
        int t_hi = (s + DC_BW) / Kk + 1;          // exclusive; ~7 elems
        const float* row = align + ((size_t)lbh * Sn + s) * (size_t)Tn;
        float acc = 0.f;
        #pragma unroll 4
        for (int t = t_lo; t < t_hi; ++t) acc += row[t];
        dc_acc = acc * sm;
    }

    // wave64 shuffle reduce -> LDS -> one store pair per block (no atomics)
    for (int off = 32; off > 0; off >>= 1) {
        mel_acc += __shfl_down(mel_acc, off);
        dc_acc  += __shfl_down(dc_acc,  off);
    }
    __shared__ float smel[BLK / 64], sdc[BLK / 64];
    int wid = threadIdx.x >> 6;
    if ((threadIdx.x & 63) == 0) { smel[wid] = mel_acc; sdc[wid] = dc_acc; }
    __syncthreads();
    if (threadIdx.x == 0) {
        float m = smel[0] + smel[1] + smel[2] + smel[3];
        float d = sdc[0]  + sdc[1]  + sdc[2]  + sdc[3];
        ws[2 * blockIdx.x]     = m;
        ws[2 * blockIdx.x + 1] = d;
    }
}

// final: reduce 1320 partial pairs + stop-BCE (16 samples) + normalization
__global__ __launch_bounds__(256) void lossB(
    const int*   __restrict__ length,
    const float* __restrict__ stop_pred,
    const float* __restrict__ ws,
    float*       __restrict__ out)
{
    float m = 0.f, d = 0.f;
    for (int i = threadIdx.x; i < GRID; i += 256) {
        float2 p = reinterpret_cast<const float2*>(ws)[i];
        m += p.x;
        d += p.y;
    }
    for (int off = 32; off > 0; off >>= 1) {
        m += __shfl_down(m, off);
        d += __shfl_down(d, off);
    }
    __shared__ float smel[4], sdc[4];
    int wid = threadIdx.x >> 6;
    if ((threadIdx.x & 63) == 0) { smel[wid] = m; sdc[wid] = d; }
    __syncthreads();
    if (threadIdx.x == 0) {
        float mel_sum = smel[0] + smel[1] + smel[2] + smel[3];
        float dc_sum  = sdc[0]  + sdc[1]  + sdc[2]  + sdc[3];
        float sum_len = 0.f, stop_sum = 0.f;
        for (int b = 0; b < Bn; ++b) {
            int len = length[b];
            sum_len += (float)len;
            float p  = stop_pred[b * Tn + (len - 1)];
            float lg = logf(p);
            if (lg < -100.f) lg = -100.f;
            stop_sum += -lg;                  // target = 1
        }
        float mel  = mel_sum / (float)(Bn * Tn * NM);
        float stop = STOP_W * stop_sum / sum_len;
        float dc   = dc_sum / ((float)Hh * sum_len);
        out[0] = mel + stop - DC_S * dc;
    }
}

extern "C" void kernel_launch(void* const* d_in, const int* in_sizes, int n_in,
                              void* d_out, int out_size, void* d_ws, size_t ws_size,
                              hipStream_t stream)
{
    const int*   length      = (const int*)  d_in[0];
    // d_in[1] = mask (bool) — recomputed from length (prefix mask by construction)
    const float* stop_pred   = (const float*)d_in[2];
    const float* mels_pred   = (const float*)d_in[3];
    const float* mels_target = (const float*)d_in[4];
    const float* align       = (const float*)d_in[5];
    float* out = (float*)d_out;
    float* ws  = (float*)d_ws;

    lossA<<<GRID, BLK, 0, stream>>>(length, mels_pred, mels_target, align, ws);
    lossB<<<1, 256, 0, stream>>>(length, stop_pred, ws, out);
}